// Round 6
// baseline (789.688 us; speedup 1.0000x reference)
//
#include <hip/hip_runtime.h>

#define NN 500000
#define FF 128
#define HH 256
#define CC 40
#define NB256 ((NN + 255) / 256)   // 1954

typedef __attribute__((ext_vector_type(8))) short bf16x8;
typedef __attribute__((ext_vector_type(4))) float f32x4;

__device__ inline unsigned short f2b(float f) {
    unsigned u = __builtin_bit_cast(unsigned, f);
    return (unsigned short)((u + 0x7FFF + ((u >> 16) & 1)) >> 16);
}
__device__ inline unsigned f2b2(float lo, float hi) {
    unsigned ul = __builtin_bit_cast(unsigned, lo);
    unsigned uh = __builtin_bit_cast(unsigned, hi);
    unsigned rl = (ul + 0x7FFF + ((ul >> 16) & 1)) >> 16;
    unsigned rh = (uh + 0x7FFF + ((uh >> 16) & 1)) >> 16;
    return rl | (rh << 16);
}

// ---------------- index / CSR kernels (unchanged) ----------------

__global__ void k_init(int* fp, int* cnt, int* cur) {
    int i = blockIdx.x * 256 + threadIdx.x;
    if (i < NN) { fp[i] = 0x7FFFFFFF; cnt[i] = 0; cur[i] = 0; }
}

__global__ void k_amin(const int* __restrict__ ei, int* fp) {
    int i = blockIdx.x * 256 + threadIdx.x;
    if (i < NN) atomicMin(&fp[ei[2 * i]], i);
}

__global__ void k_count(const int* __restrict__ ei, const int* __restrict__ fp,
                        int* __restrict__ bsums) {
    int i = blockIdx.x * 256 + threadIdx.x;
    int f = 0;
    if (i < NN) f = (fp[ei[2 * i]] == i) ? 1 : 0;
    __shared__ int sh[256];
    sh[threadIdx.x] = f;
    __syncthreads();
    for (int s = 128; s > 0; s >>= 1) {
        if (threadIdx.x < s) sh[threadIdx.x] += sh[threadIdx.x + s];
        __syncthreads();
    }
    if (threadIdx.x == 0) bsums[blockIdx.x] = sh[0];
}

__global__ void k_scan(const int* __restrict__ bsums, int* __restrict__ bofs, int nb) {
    __shared__ int sh[256];
    int carry = 0;
    for (int base = 0; base < nb; base += 256) {
        int i = base + threadIdx.x;
        int v = (i < nb) ? bsums[i] : 0;
        sh[threadIdx.x] = v;
        __syncthreads();
        for (int s = 1; s < 256; s <<= 1) {
            int t = (threadIdx.x >= s) ? sh[threadIdx.x - s] : 0;
            __syncthreads();
            sh[threadIdx.x] += t;
            __syncthreads();
        }
        if (i < nb) bofs[i] = carry + sh[threadIdx.x] - v;   // exclusive
        carry += sh[255];
        __syncthreads();
    }
}

__global__ void k_rank(const int* __restrict__ ei, const int* __restrict__ fp,
                       const int* __restrict__ bofs, int* __restrict__ rank) {
    int i = blockIdx.x * 256 + threadIdx.x;
    int s = 0, f = 0;
    if (i < NN) { s = ei[2 * i]; f = (fp[s] == i) ? 1 : 0; }
    __shared__ int sh[256];
    sh[threadIdx.x] = f;
    __syncthreads();
    for (int st = 1; st < 256; st <<= 1) {
        int t = (threadIdx.x >= st) ? sh[threadIdx.x - st] : 0;
        __syncthreads();
        sh[threadIdx.x] += t;
        __syncthreads();
    }
    if (f) rank[s] = bofs[blockIdx.x] + sh[threadIdx.x] - 1;
}

__global__ void k_mapped(const int* __restrict__ ei, const int* __restrict__ rank,
                         int* __restrict__ mapped, int* __restrict__ cnt) {
    int i = blockIdx.x * 256 + threadIdx.x;
    if (i < NN) {
        int s1 = ei[2 * i];
        int s2 = ei[2 * (long long)s1];
        int m = rank[s2];
        mapped[i] = m;
        atomicAdd(&cnt[m], 1);
    }
}

__global__ void k_block_scan(const int* __restrict__ in, int* __restrict__ outp,
                             int* __restrict__ bsums, int n) {
    int i = blockIdx.x * 256 + threadIdx.x;
    int v = (i < n) ? in[i] : 0;
    __shared__ int sh[256];
    sh[threadIdx.x] = v;
    __syncthreads();
    for (int s = 1; s < 256; s <<= 1) {
        int t = (threadIdx.x >= s) ? sh[threadIdx.x - s] : 0;
        __syncthreads();
        sh[threadIdx.x] += t;
        __syncthreads();
    }
    if (i < n) outp[i] = sh[threadIdx.x] - v;     // exclusive within block
    if (threadIdx.x == 255) bsums[blockIdx.x] = sh[255];
}

__global__ void k_add_off(int* __restrict__ outp, const int* __restrict__ bofs, int n) {
    int i = blockIdx.x * 256 + threadIdx.x;
    if (i < n) outp[i] += bofs[blockIdx.x];
    if (i == 0) outp[n] = n;                      // rowptr[NN] = NN (total edges)
}

__global__ void k_scatter(const int* __restrict__ mapped, const int* __restrict__ rowptr,
                          int* __restrict__ cur, int* __restrict__ col) {
    int i = blockIdx.x * 256 + threadIdx.x;
    if (i < NN) {
        int m = mapped[i];
        int loc = rowptr[m] + atomicAdd(&cur[m], 1);
        col[loc] = i;
    }
}

// W1T[n][k] n<HH k<FF ; W2T[n][k] n<48 (pad 0), k<HH
__global__ void k_cvt(const float* __restrict__ W1, const float* __restrict__ W2,
                      unsigned short* __restrict__ W1T, unsigned short* __restrict__ W2T) {
    int i = blockIdx.x * 256 + threadIdx.x;
    if (i < HH * FF) {
        int n = i >> 7, k = i & 127;
        W1T[i] = f2b(W1[k * HH + n]);
    }
    int j = i - HH * FF;
    if (j >= 0 && j < 48 * HH) {
        int n = j >> 8, k = j & 255;
        W2T[j] = (n < CC) ? f2b(W2[k * CC + n]) : (unsigned short)0;
    }
}

// ---------------- fused stage: per 64-segment block, 512 threads ----------------
// Each wave gathers ITS OWN A-fragment rows (mt*16..+15) straight to registers:
// no x LDS staging, no pre-MFMA barriers (4 -> 2 barriers/chunk), no LDS
// bank-conflicts on the gather path. The two half-waves of an m-tile read the
// same 64B lines (L1/MSHR-merged), so HBM traffic is unchanged.

__global__ __launch_bounds__(512, 2) void k_fused(
    const float* __restrict__ x, const unsigned short* __restrict__ W1T,
    const float* __restrict__ b1, const unsigned short* __restrict__ W2T,
    const float* __restrict__ b2, const int* __restrict__ rowptr,
    const int* __restrict__ col, float* __restrict__ out)
{
    __shared__ __align__(16) unsigned short Buf[64][264];   // h-tile / A2-tile
    __shared__ int rp[65];
    const int tid = threadIdx.x;
    const long long m0 = (long long)blockIdx.x * 64;

    if (tid < 65) {
        long long mi = m0 + tid; if (mi > NN) mi = NN;
        rp[tid] = rowptr[mi];
    }
    __syncthreads();
    const int e0 = rp[0], e1 = rp[64];

    if (e0 == e1) {   // all 64 segments empty: out rows = b2
        for (int t = tid; t < 64 * CC; t += 512) {
            int r = t / CC, c = t % CC;
            long long m = m0 + r;
            if (m < NN) out[m * CC + c] = b2[c];
        }
        return;
    }

    const int lane = tid & 63, wave = tid >> 6;
    const int l16 = lane & 15, quad = lane >> 4;
    const int mt = wave & 3, half = wave >> 2;      // m-tile, n-half for MFMA phases
    const int cg = tid & 15, ms = tid >> 4;         // segsum layout: ms in [0,32)

    float s[2][16];
#pragma unroll
    for (int p = 0; p < 2; ++p)
#pragma unroll
        for (int t = 0; t < 16; ++t) s[p][t] = 0.f;

    for (int cb = e0; cb < e1; cb += 64) {
        // ---- gather this wave's 16 A-rows directly to registers ----
        int j = cb + mt * 16 + l16;
        int e = (j < e1) ? col[j] : col[e1 - 1];    // clamped rows never accumulated
        const float4* src4 = (const float4*)(x + (long long)e * FF);
        float4 fa[4], fb[4];
#pragma unroll
        for (int kk = 0; kk < 4; ++kk) {
            fa[kk] = src4[kk * 8 + quad * 2];
            fb[kk] = src4[kk * 8 + quad * 2 + 1];
        }
        bf16x8 a[4];
#pragma unroll
        for (int kk = 0; kk < 4; ++kk) {
            uint4 u;
            u.x = f2b2(fa[kk].x, fa[kk].y);
            u.y = f2b2(fa[kk].z, fa[kk].w);
            u.z = f2b2(fb[kk].x, fb[kk].y);
            u.w = f2b2(fb[kk].z, fb[kk].w);
            a[kk] = __builtin_bit_cast(bf16x8, u);
        }

        // ---- h-tile = relu(A @ W1 + b1); wave covers (mt, half) quadrant ----
#pragma unroll
        for (int ntl = 0; ntl < 8; ++ntl) {
            int n16 = half * 128 + ntl * 16 + l16;
            f32x4 acc = {0, 0, 0, 0};
#pragma unroll
            for (int kk = 0; kk < 4; ++kk) {
                bf16x8 b = *(const bf16x8*)(W1T + (long long)n16 * FF + kk * 32 + quad * 8);
                acc = __builtin_amdgcn_mfma_f32_16x16x32_bf16(a[kk], b, acc, 0, 0, 0);
            }
            float bias = b1[n16];
#pragma unroll
            for (int reg = 0; reg < 4; ++reg) {   // C/D: row=quad*4+reg, col=l16
                float v = acc[reg] + bias;
                Buf[mt * 16 + quad * 4 + reg][half * 128 + ntl * 16 + l16] =
                    f2b(v > 0.f ? v : 0.f);
            }
        }
        __syncthreads();

        // ---- accumulate h rows into per-thread segment partials ----
        {
            int ce = min(e1, cb + 64);
#pragma unroll
            for (int p = 0; p < 2; ++p) {
                int m = p * 32 + ms;
                int a0 = max(rp[m], cb), a1 = min(rp[m + 1], ce);
                for (int ee = a0; ee < a1; ++ee) {
                    const uint4* src = (const uint4*)&Buf[ee - cb][cg * 16];
                    uint4 u0 = src[0], u1 = src[1];
                    unsigned w[8] = {u0.x, u0.y, u0.z, u0.w, u1.x, u1.y, u1.z, u1.w};
#pragma unroll
                    for (int t = 0; t < 8; ++t) {
                        s[p][2 * t]     += __builtin_bit_cast(float, w[t] << 16);
                        s[p][2 * t + 1] += __builtin_bit_cast(float, w[t] & 0xFFFF0000u);
                    }
                }
            }
        }
        __syncthreads();   // h-tile consumed; next chunk may overwrite Buf
    }

    // ---- relu + convert, stage A for W2 GEMM (reuse Buf) ----
#pragma unroll
    for (int p = 0; p < 2; ++p) {
        int m = p * 32 + ms;
        unsigned* dst = (unsigned*)&Buf[m][cg * 16];
#pragma unroll
        for (int t = 0; t < 8; ++t)
            dst[t] = f2b2(s[p][2 * t] > 0.f ? s[p][2 * t] : 0.f,
                          s[p][2 * t + 1] > 0.f ? s[p][2 * t + 1] : 0.f);
    }
    __syncthreads();

    bf16x8 a2[8];
#pragma unroll
    for (int kk = 0; kk < 8; ++kk)
        a2[kk] = *(const bf16x8*)&Buf[mt * 16 + l16][kk * 32 + quad * 8];

    // W2 GEMM: waves with half==0 compute nt=0; half==1 compute nt=1,2
    if (half == 0) {
        f32x4 acc = {};
#pragma unroll
        for (int kk = 0; kk < 8; ++kk) {
            bf16x8 b = *(const bf16x8*)(W2T + (0 * 16 + l16) * HH + kk * 32 + quad * 8);
            acc = __builtin_amdgcn_mfma_f32_16x16x32_bf16(a2[kk], b, acc, 0, 0, 0);
        }
        int n = l16;
        float bias = b2[n];
#pragma unroll
        for (int reg = 0; reg < 4; ++reg) {
            long long m = m0 + mt * 16 + quad * 4 + reg;
            if (m < NN) out[m * CC + n] = acc[reg] + bias;
        }
    } else {
        f32x4 acc[2] = {};
#pragma unroll
        for (int kk = 0; kk < 8; ++kk) {
#pragma unroll
            for (int nt = 0; nt < 2; ++nt) {
                bf16x8 b = *(const bf16x8*)(W2T + ((nt + 1) * 16 + l16) * HH + kk * 32 + quad * 8);
                acc[nt] = __builtin_amdgcn_mfma_f32_16x16x32_bf16(a2[kk], b, acc[nt], 0, 0, 0);
            }
        }
#pragma unroll
        for (int nt = 0; nt < 2; ++nt) {
            int n = (nt + 1) * 16 + l16;
            if (n < CC) {
                float bias = b2[n];
#pragma unroll
                for (int reg = 0; reg < 4; ++reg) {
                    long long m = m0 + mt * 16 + quad * 4 + reg;
                    if (m < NN) out[m * CC + n] = acc[nt][reg] + bias;
                }
            }
        }
    }
}

// ---------------- launch ----------------

extern "C" void kernel_launch(void* const* d_in, const int* in_sizes, int n_in,
                              void* d_out, int out_size, void* d_ws, size_t ws_size,
                              hipStream_t stream) {
    const float* x  = (const float*)d_in[0];
    const int*   ei = (const int*)d_in[1];
    const float* W1 = (const float*)d_in[2];
    const float* b1 = (const float*)d_in[3];
    const float* W2 = (const float*)d_in[4];
    const float* b2 = (const float*)d_in[5];
    float* out = (float*)d_out;

    char* ws = (char*)d_ws;
    size_t off = 0;
    auto alloc = [&](size_t bytes) { void* p = ws + off; off = (off + bytes + 255) & ~(size_t)255; return p; };
    int* fp     = (int*)alloc(4ll * NN);
    int* rank   = (int*)alloc(4ll * NN);
    int* mapped = (int*)alloc(4ll * NN);
    int* cnt    = (int*)alloc(4ll * NN);
    int* cur    = (int*)alloc(4ll * NN);
    int* rowptr = (int*)alloc(4ll * (NN + 2));
    int* col    = (int*)alloc(4ll * (NN + 64));
    int* bsums  = (int*)alloc(4ll * 2048);
    int* bofs   = (int*)alloc(4ll * 2048);
    unsigned short* W1T = (unsigned short*)alloc(2ll * HH * FF);
    unsigned short* W2T = (unsigned short*)alloc(2ll * 48 * HH);

    hipLaunchKernelGGL(k_init,   dim3(NB256), dim3(256), 0, stream, fp, cnt, cur);
    hipLaunchKernelGGL(k_amin,   dim3(NB256), dim3(256), 0, stream, ei, fp);
    hipLaunchKernelGGL(k_count,  dim3(NB256), dim3(256), 0, stream, ei, fp, bsums);
    hipLaunchKernelGGL(k_scan,   dim3(1),     dim3(256), 0, stream, bsums, bofs, NB256);
    hipLaunchKernelGGL(k_rank,   dim3(NB256), dim3(256), 0, stream, ei, fp, bofs, rank);
    hipLaunchKernelGGL(k_mapped, dim3(NB256), dim3(256), 0, stream, ei, rank, mapped, cnt);
    hipLaunchKernelGGL(k_block_scan, dim3(NB256), dim3(256), 0, stream, cnt, rowptr, bsums, NN);
    hipLaunchKernelGGL(k_scan,   dim3(1),     dim3(256), 0, stream, bsums, bofs, NB256);
    hipLaunchKernelGGL(k_add_off,dim3(NB256), dim3(256), 0, stream, rowptr, bofs, NN);
    hipLaunchKernelGGL(k_scatter,dim3(NB256), dim3(256), 0, stream, mapped, rowptr, cur, col);
    hipLaunchKernelGGL(k_cvt,    dim3((HH * FF + 48 * HH + 255) / 256), dim3(256), 0, stream,
                       W1, W2, W1T, W2T);

    const int NB64 = (NN + 63) / 64;    // 7813
    hipLaunchKernelGGL(k_fused, dim3(NB64), dim3(512), 0, stream,
                       x, W1T, b1, W2T, b2, rowptr, col, out);
}

// Round 7
// 707.386 us; speedup vs baseline: 1.1163x; 1.1163x over previous
//
#include <hip/hip_runtime.h>

#define NN 500000
#define FF 128
#define HH 256
#define CC 40
#define NB256 ((NN + 255) / 256)   // 1954

typedef __attribute__((ext_vector_type(8))) short bf16x8;
typedef __attribute__((ext_vector_type(4))) float f32x4;

__device__ inline unsigned short f2b(float f) {
    unsigned u = __builtin_bit_cast(unsigned, f);
    return (unsigned short)((u + 0x7FFF + ((u >> 16) & 1)) >> 16);
}
__device__ inline unsigned f2b2(float lo, float hi) {
    unsigned ul = __builtin_bit_cast(unsigned, lo);
    unsigned uh = __builtin_bit_cast(unsigned, hi);
    unsigned rl = (ul + 0x7FFF + ((ul >> 16) & 1)) >> 16;
    unsigned rh = (uh + 0x7FFF + ((uh >> 16) & 1)) >> 16;
    return rl | (rh << 16);
}

// ---------------- index / CSR kernels (unchanged) ----------------

__global__ void k_init(int* fp, int* cnt, int* cur) {
    int i = blockIdx.x * 256 + threadIdx.x;
    if (i < NN) { fp[i] = 0x7FFFFFFF; cnt[i] = 0; cur[i] = 0; }
}

__global__ void k_amin(const int* __restrict__ ei, int* fp) {
    int i = blockIdx.x * 256 + threadIdx.x;
    if (i < NN) atomicMin(&fp[ei[2 * i]], i);
}

__global__ void k_count(const int* __restrict__ ei, const int* __restrict__ fp,
                        int* __restrict__ bsums) {
    int i = blockIdx.x * 256 + threadIdx.x;
    int f = 0;
    if (i < NN) f = (fp[ei[2 * i]] == i) ? 1 : 0;
    __shared__ int sh[256];
    sh[threadIdx.x] = f;
    __syncthreads();
    for (int s = 128; s > 0; s >>= 1) {
        if (threadIdx.x < s) sh[threadIdx.x] += sh[threadIdx.x + s];
        __syncthreads();
    }
    if (threadIdx.x == 0) bsums[blockIdx.x] = sh[0];
}

__global__ void k_scan(const int* __restrict__ bsums, int* __restrict__ bofs, int nb) {
    __shared__ int sh[256];
    int carry = 0;
    for (int base = 0; base < nb; base += 256) {
        int i = base + threadIdx.x;
        int v = (i < nb) ? bsums[i] : 0;
        sh[threadIdx.x] = v;
        __syncthreads();
        for (int s = 1; s < 256; s <<= 1) {
            int t = (threadIdx.x >= s) ? sh[threadIdx.x - s] : 0;
            __syncthreads();
            sh[threadIdx.x] += t;
            __syncthreads();
        }
        if (i < nb) bofs[i] = carry + sh[threadIdx.x] - v;   // exclusive
        carry += sh[255];
        __syncthreads();
    }
}

__global__ void k_rank(const int* __restrict__ ei, const int* __restrict__ fp,
                       const int* __restrict__ bofs, int* __restrict__ rank) {
    int i = blockIdx.x * 256 + threadIdx.x;
    int s = 0, f = 0;
    if (i < NN) { s = ei[2 * i]; f = (fp[s] == i) ? 1 : 0; }
    __shared__ int sh[256];
    sh[threadIdx.x] = f;
    __syncthreads();
    for (int st = 1; st < 256; st <<= 1) {
        int t = (threadIdx.x >= st) ? sh[threadIdx.x - st] : 0;
        __syncthreads();
        sh[threadIdx.x] += t;
        __syncthreads();
    }
    if (f) rank[s] = bofs[blockIdx.x] + sh[threadIdx.x] - 1;
}

__global__ void k_mapped(const int* __restrict__ ei, const int* __restrict__ rank,
                         int* __restrict__ mapped, int* __restrict__ cnt) {
    int i = blockIdx.x * 256 + threadIdx.x;
    if (i < NN) {
        int s1 = ei[2 * i];
        int s2 = ei[2 * (long long)s1];
        int m = rank[s2];
        mapped[i] = m;
        atomicAdd(&cnt[m], 1);
    }
}

__global__ void k_block_scan(const int* __restrict__ in, int* __restrict__ outp,
                             int* __restrict__ bsums, int n) {
    int i = blockIdx.x * 256 + threadIdx.x;
    int v = (i < n) ? in[i] : 0;
    __shared__ int sh[256];
    sh[threadIdx.x] = v;
    __syncthreads();
    for (int s = 1; s < 256; s <<= 1) {
        int t = (threadIdx.x >= s) ? sh[threadIdx.x - s] : 0;
        __syncthreads();
        sh[threadIdx.x] += t;
        __syncthreads();
    }
    if (i < n) outp[i] = sh[threadIdx.x] - v;     // exclusive within block
    if (threadIdx.x == 255) bsums[blockIdx.x] = sh[255];
}

__global__ void k_add_off(int* __restrict__ outp, const int* __restrict__ bofs, int n) {
    int i = blockIdx.x * 256 + threadIdx.x;
    if (i < n) outp[i] += bofs[blockIdx.x];
    if (i == 0) outp[n] = n;                      // rowptr[NN] = NN (total edges)
}

__global__ void k_scatter(const int* __restrict__ mapped, const int* __restrict__ rowptr,
                          int* __restrict__ cur, int* __restrict__ col) {
    int i = blockIdx.x * 256 + threadIdx.x;
    if (i < NN) {
        int m = mapped[i];
        int loc = rowptr[m] + atomicAdd(&cur[m], 1);
        col[loc] = i;
    }
}

// W1T[n][k] n<HH k<FF ; W2T[n][k] n<48 (pad 0), k<HH
__global__ void k_cvt(const float* __restrict__ W1, const float* __restrict__ W2,
                      unsigned short* __restrict__ W1T, unsigned short* __restrict__ W2T) {
    int i = blockIdx.x * 256 + threadIdx.x;
    if (i < HH * FF) {
        int n = i >> 7, k = i & 127;
        W1T[i] = f2b(W1[k * HH + n]);
    }
    int j = i - HH * FF;
    if (j >= 0 && j < 48 * HH) {
        int n = j >> 8, k = j & 255;
        W2T[j] = (n < CC) ? f2b(W2[k * CC + n]) : (unsigned short)0;
    }
}

// ---------------- fused stage: per 32-segment block, 256 threads ----------------
// Round-4 structure (cooperative LDS staging + register prefetch of next chunk's
// gather), halved block: same per-thread register state (~116 VGPR) keeps
// 16 waves/CU, but as FOUR independent blocks instead of two -> 2x concurrent
// gather latency chains per CU, smaller barrier groups, finer empty-block skip.
// No min-waves clause: a declared 128-VGPR cap previously triggered a
// pathological spill (1 GB scratch round-trip); natural allocation fits <128.

__global__ __launch_bounds__(256) void k_fused(
    const float* __restrict__ x, const unsigned short* __restrict__ W1T,
    const float* __restrict__ b1, const unsigned short* __restrict__ W2T,
    const float* __restrict__ b2, const int* __restrict__ rowptr,
    const int* __restrict__ col, float* __restrict__ out)
{
    __shared__ __align__(16) unsigned short Buf[32][264];   // x-tile / h-tile / A2-tile
    __shared__ int rp[33];
    const int tid = threadIdx.x;
    const long long m0 = (long long)blockIdx.x * 32;

    if (tid < 33) {
        long long mi = m0 + tid; if (mi > NN) mi = NN;
        rp[tid] = rowptr[mi];
    }
    __syncthreads();
    const int e0 = rp[0], e1 = rp[32];

    if (e0 == e1) {   // all 32 segments empty: out rows = b2
        for (int t = tid; t < 32 * CC; t += 256) {
            int r = t / CC, c = t % CC;
            long long m = m0 + r;
            if (m < NN) out[m * CC + c] = b2[c];
        }
        return;
    }

    const int lane = tid & 63, wave = tid >> 6;
    const int l16 = lane & 15, quad = lane >> 4;
    const int mt = wave & 1, half = wave >> 1;      // m-tile (2x16), n-half (2x128)
    const int cg = tid & 15, ms = tid >> 4;         // segsum layout: ms in [0,16)
    const int gr = tid >> 3, gq = tid & 7;          // gather layout: 8 threads/row

    float s[2][16];
#pragma unroll
    for (int p = 0; p < 2; ++p)
#pragma unroll
        for (int t = 0; t < 16; ++t) s[p][t] = 0.f;

    float4 rv[4];
    auto issue_gather = [&](int cb) {
        long long j = (long long)cb + gr;
        int e = (j < e1) ? col[j] : col[e1 - 1];    // clamped rows never accumulated
        const float4* src = (const float4*)(x + (long long)e * FF + gq * 16);
        rv[0] = src[0]; rv[1] = src[1]; rv[2] = src[2]; rv[3] = src[3];
    };

    issue_gather(e0);

    for (int cb = e0; cb < e1; cb += 32) {
        // ---- write prefetched x rows (bf16) into Buf ----
        {
            unsigned* dst = (unsigned*)&Buf[gr][gq * 16];
#pragma unroll
            for (int t = 0; t < 4; ++t) {
                dst[t * 2]     = f2b2(rv[t].x, rv[t].y);
                dst[t * 2 + 1] = f2b2(rv[t].z, rv[t].w);
            }
        }
        __syncthreads();

        bf16x8 a[4];
#pragma unroll
        for (int kk = 0; kk < 4; ++kk)
            a[kk] = *(const bf16x8*)&Buf[mt * 16 + l16][kk * 32 + quad * 8];

        if (cb + 32 < e1) issue_gather(cb + 32);    // overlap gather with MFMA below
        __syncthreads();   // A frags in regs; Buf reusable for h staging

        // ---- h-tile = relu(A @ W1 + b1); wave covers (mt, half) quadrant ----
#pragma unroll
        for (int ntl = 0; ntl < 8; ++ntl) {
            int n16 = half * 128 + ntl * 16 + l16;
            f32x4 acc = {0, 0, 0, 0};
#pragma unroll
            for (int kk = 0; kk < 4; ++kk) {
                bf16x8 b = *(const bf16x8*)(W1T + (long long)n16 * FF + kk * 32 + quad * 8);
                acc = __builtin_amdgcn_mfma_f32_16x16x32_bf16(a[kk], b, acc, 0, 0, 0);
            }
            float bias = b1[n16];
#pragma unroll
            for (int reg = 0; reg < 4; ++reg) {   // C/D: row=quad*4+reg, col=l16
                float v = acc[reg] + bias;
                Buf[mt * 16 + quad * 4 + reg][half * 128 + ntl * 16 + l16] =
                    f2b(v > 0.f ? v : 0.f);
            }
        }
        __syncthreads();

        // ---- accumulate h rows into per-thread segment partials ----
        {
            int ce = min(e1, cb + 32);
#pragma unroll
            for (int p = 0; p < 2; ++p) {
                int m = p * 16 + ms;
                int a0 = max(rp[m], cb), a1 = min(rp[m + 1], ce);
                for (int ee = a0; ee < a1; ++ee) {
                    const uint4* src = (const uint4*)&Buf[ee - cb][cg * 16];
                    uint4 u0 = src[0], u1 = src[1];
                    unsigned w[8] = {u0.x, u0.y, u0.z, u0.w, u1.x, u1.y, u1.z, u1.w};
#pragma unroll
                    for (int t = 0; t < 8; ++t) {
                        s[p][2 * t]     += __builtin_bit_cast(float, w[t] << 16);
                        s[p][2 * t + 1] += __builtin_bit_cast(float, w[t] & 0xFFFF0000u);
                    }
                }
            }
        }
        __syncthreads();   // h-tile consumed; next chunk may overwrite Buf
    }

    // ---- relu + convert, stage A for W2 GEMM (reuse Buf) ----
#pragma unroll
    for (int p = 0; p < 2; ++p) {
        int m = p * 16 + ms;
        unsigned* dst = (unsigned*)&Buf[m][cg * 16];
#pragma unroll
        for (int t = 0; t < 8; ++t)
            dst[t] = f2b2(s[p][2 * t] > 0.f ? s[p][2 * t] : 0.f,
                          s[p][2 * t + 1] > 0.f ? s[p][2 * t + 1] : 0.f);
    }
    __syncthreads();

    bf16x8 a2[8];
#pragma unroll
    for (int kk = 0; kk < 8; ++kk)
        a2[kk] = *(const bf16x8*)&Buf[mt * 16 + l16][kk * 32 + quad * 8];

    // W2 GEMM: waves with half==0 compute nt=0; half==1 compute nt=1,2
    if (half == 0) {
        f32x4 acc = {};
#pragma unroll
        for (int kk = 0; kk < 8; ++kk) {
            bf16x8 b = *(const bf16x8*)(W2T + (0 * 16 + l16) * HH + kk * 32 + quad * 8);
            acc = __builtin_amdgcn_mfma_f32_16x16x32_bf16(a2[kk], b, acc, 0, 0, 0);
        }
        int n = l16;
        float bias = b2[n];
#pragma unroll
        for (int reg = 0; reg < 4; ++reg) {
            long long m = m0 + mt * 16 + quad * 4 + reg;
            if (m < NN) out[m * CC + n] = acc[reg] + bias;
        }
    } else {
        f32x4 acc[2] = {};
#pragma unroll
        for (int kk = 0; kk < 8; ++kk) {
#pragma unroll
            for (int nt = 0; nt < 2; ++nt) {
                bf16x8 b = *(const bf16x8*)(W2T + ((nt + 1) * 16 + l16) * HH + kk * 32 + quad * 8);
                acc[nt] = __builtin_amdgcn_mfma_f32_16x16x32_bf16(a2[kk], b, acc[nt], 0, 0, 0);
            }
        }
#pragma unroll
        for (int nt = 0; nt < 2; ++nt) {
            int n = (nt + 1) * 16 + l16;
            if (n < CC) {
                float bias = b2[n];
#pragma unroll
                for (int reg = 0; reg < 4; ++reg) {
                    long long m = m0 + mt * 16 + quad * 4 + reg;
                    if (m < NN) out[m * CC + n] = acc[nt][reg] + bias;
                }
            }
        }
    }
}

// ---------------- launch ----------------

extern "C" void kernel_launch(void* const* d_in, const int* in_sizes, int n_in,
                              void* d_out, int out_size, void* d_ws, size_t ws_size,
                              hipStream_t stream) {
    const float* x  = (const float*)d_in[0];
    const int*   ei = (const int*)d_in[1];
    const float* W1 = (const float*)d_in[2];
    const float* b1 = (const float*)d_in[3];
    const float* W2 = (const float*)d_in[4];
    const float* b2 = (const float*)d_in[5];
    float* out = (float*)d_out;

    char* ws = (char*)d_ws;
    size_t off = 0;
    auto alloc = [&](size_t bytes) { void* p = ws + off; off = (off + bytes + 255) & ~(size_t)255; return p; };
    int* fp     = (int*)alloc(4ll * NN);
    int* rank   = (int*)alloc(4ll * NN);
    int* mapped = (int*)alloc(4ll * NN);
    int* cnt    = (int*)alloc(4ll * NN);
    int* cur    = (int*)alloc(4ll * NN);
    int* rowptr = (int*)alloc(4ll * (NN + 2));
    int* col    = (int*)alloc(4ll * (NN + 64));
    int* bsums  = (int*)alloc(4ll * 2048);
    int* bofs   = (int*)alloc(4ll * 2048);
    unsigned short* W1T = (unsigned short*)alloc(2ll * HH * FF);
    unsigned short* W2T = (unsigned short*)alloc(2ll * 48 * HH);

    hipLaunchKernelGGL(k_init,   dim3(NB256), dim3(256), 0, stream, fp, cnt, cur);
    hipLaunchKernelGGL(k_amin,   dim3(NB256), dim3(256), 0, stream, ei, fp);
    hipLaunchKernelGGL(k_count,  dim3(NB256), dim3(256), 0, stream, ei, fp, bsums);
    hipLaunchKernelGGL(k_scan,   dim3(1),     dim3(256), 0, stream, bsums, bofs, NB256);
    hipLaunchKernelGGL(k_rank,   dim3(NB256), dim3(256), 0, stream, ei, fp, bofs, rank);
    hipLaunchKernelGGL(k_mapped, dim3(NB256), dim3(256), 0, stream, ei, rank, mapped, cnt);
    hipLaunchKernelGGL(k_block_scan, dim3(NB256), dim3(256), 0, stream, cnt, rowptr, bsums, NN);
    hipLaunchKernelGGL(k_scan,   dim3(1),     dim3(256), 0, stream, bsums, bofs, NB256);
    hipLaunchKernelGGL(k_add_off,dim3(NB256), dim3(256), 0, stream, rowptr, bofs, NN);
    hipLaunchKernelGGL(k_scatter,dim3(NB256), dim3(256), 0, stream, mapped, rowptr, cur, col);
    hipLaunchKernelGGL(k_cvt,    dim3((HH * FF + 48 * HH + 255) / 256), dim3(256), 0, stream,
                       W1, W2, W1T, W2T);

    const int NB32 = (NN + 31) / 32;    // 15625
    hipLaunchKernelGGL(k_fused, dim3(NB32), dim3(256), 0, stream,
                       x, W1T, b1, W2T, b2, rowptr, col, out);
}